// Round 1
// baseline (707.281 us; speedup 1.0000x reference)
//
#include <hip/hip_runtime.h>

// Problem constants (from reference)
constexpr int N_NODES = 100000;
constexpr int N_EDGES = 1600000;
constexpr int D = 64;          // D_IN == D_OUT == 64

// ---------------------------------------------------------------------------
// Kernel 0: zero the output accumulator (d_out) and the degree array (d_ws).
// Harness poisons both with 0xAA before every timed launch.
// ---------------------------------------------------------------------------
__global__ __launch_bounds__(256) void zero_kernel(float4* __restrict__ out4,
                                                   float* __restrict__ deg) {
    const int stride = gridDim.x * blockDim.x;
    int i = blockIdx.x * blockDim.x + threadIdx.x;
    const int total4 = (N_NODES * D) / 4;   // 1,600,000 float4s
    for (int idx = i; idx < total4; idx += stride)
        out4[idx] = make_float4(0.f, 0.f, 0.f, 0.f);
    for (int idx = i; idx < N_NODES; idx += stride)
        deg[idx] = 0.f;
}

// ---------------------------------------------------------------------------
// Kernel 1: edge scatter. One wave (64 lanes) per edge; lane j handles
// feature j. Coalesced 256B read of feat[src], 64 f32 atomics into out[dst].
// Degree counted once per edge by lane 0.
// ---------------------------------------------------------------------------
__global__ __launch_bounds__(256) void scatter_kernel(
    const float* __restrict__ feat, const int* __restrict__ src,
    const int* __restrict__ dst, const float* __restrict__ ew,
    float* __restrict__ out, float* __restrict__ deg) {
    const int gid  = blockIdx.x * blockDim.x + threadIdx.x;
    const int e    = gid >> 6;
    const int lane = gid & 63;
    if (e >= N_EDGES) return;
    const int s = src[e];
    const int d = dst[e];
    const float w = ew[e];
    const float v = feat[(size_t)s * D + lane] * w;
    atomicAdd(&out[(size_t)d * D + lane], v);
    if (lane == 0) atomicAdd(&deg[d], 1.0f);
}

// ---------------------------------------------------------------------------
// Kernel 2: per-node finalize, in place on d_out.
// out[n,:] = feat[n,:] @ Ws^T  +  (out[n,:] @ Wn^T) / max(deg[n],1)  + bias
// One wave per node; lane j owns output feature j. W matrices staged in LDS
// with +1 padding: address lane*65+k -> bank (lane+k)%32, 2-way (free).
// Row values broadcast across the wave via __shfl.
// ---------------------------------------------------------------------------
__global__ __launch_bounds__(256) void finalize_kernel(
    const float* __restrict__ feat, const float* __restrict__ Wn,
    const float* __restrict__ Ws, const float* __restrict__ bias,
    const float* __restrict__ deg, float* __restrict__ out) {
    __shared__ float lWn[D * 65];
    __shared__ float lWs[D * 65];

    for (int idx = threadIdx.x; idx < D * D; idx += 256) {
        const int r = idx >> 6, c = idx & 63;
        lWn[r * 65 + c] = Wn[idx];
        lWs[r * 65 + c] = Ws[idx];
    }
    __syncthreads();

    const int wave = threadIdx.x >> 6;
    const int lane = threadIdx.x & 63;
    const int n = blockIdx.x * 4 + wave;
    if (n >= N_NODES) return;

    const float f  = feat[(size_t)n * D + lane];
    const float sv = out[(size_t)n * D + lane];
    const float inv = 1.0f / fmaxf(deg[n], 1.0f);

    const float* __restrict__ wsrow = &lWs[lane * 65];
    const float* __restrict__ wnrow = &lWn[lane * 65];

    float acc_s = 0.f;
    float acc_n = 0.f;
#pragma unroll
    for (int k = 0; k < D; ++k) {
        const float fk  = __shfl(f,  k);
        const float svk = __shfl(sv, k);
        acc_s += fk  * wsrow[k];
        acc_n += svk * wnrow[k];
    }
    out[(size_t)n * D + lane] = acc_s + acc_n * inv + bias[lane];
}

// ---------------------------------------------------------------------------
extern "C" void kernel_launch(void* const* d_in, const int* in_sizes, int n_in,
                              void* d_out, int out_size, void* d_ws, size_t ws_size,
                              hipStream_t stream) {
    const float* feat = (const float*)d_in[0];
    const int*   src  = (const int*)  d_in[1];
    const int*   dst  = (const int*)  d_in[2];
    const float* ew   = (const float*)d_in[3];
    const float* Wn   = (const float*)d_in[4];
    const float* Ws   = (const float*)d_in[5];
    const float* bias = (const float*)d_in[6];
    float* out = (float*)d_out;
    float* deg = (float*)d_ws;   // 100000 floats = 400 KB scratch

    zero_kernel<<<2048, 256, 0, stream>>>((float4*)out, deg);

    const int scatter_blocks = (N_EDGES * 64) / 256;   // 400,000
    scatter_kernel<<<scatter_blocks, 256, 0, stream>>>(feat, src, dst, ew, out, deg);

    const int fin_blocks = (N_NODES + 3) / 4;          // 25,000
    finalize_kernel<<<fin_blocks, 256, 0, stream>>>(feat, Wn, Ws, bias, deg, out);
}

// Round 2
// 412.337 us; speedup vs baseline: 1.7153x; 1.7153x over previous
//
#include <hip/hip_runtime.h>

// Problem constants (from reference)
constexpr int N_NODES = 100000;
constexpr int N_EDGES = 1600000;
constexpr int D = 64;          // D_IN == D_OUT == 64

// ---------------------------------------------------------------------------
// Workspace layout (bytes). cnt and cursor alias the same region:
// hist writes cnt; scan1 consumes cnt; scan3 rewrites it as cursor.
// ---------------------------------------------------------------------------
constexpr size_t OFF_STARTS  = 0;                                  // (N_NODES+1) int
constexpr size_t OFF_CURSOR  = 400016;                             // N_NODES int (aka cnt)
constexpr size_t OFF_BSUM    = 800032;                             // 128 int
constexpr size_t OFF_BOFF    = 800544;                             // 128 int
constexpr size_t OFF_ENTRIES = 1048576;                            // N_EDGES uint2 = 12.8 MB
constexpr size_t OFF_AGG     = 14680064;                           // N_NODES*64 float = 25.6 MB
constexpr size_t WS_NEEDED   = OFF_AGG + (size_t)N_NODES * D * 4;  // 40,280,064 B

constexpr int SCAN_TILE = 1024;                                     // elems per scan block
constexpr int NB_SCAN   = (N_NODES + SCAN_TILE - 1) / SCAN_TILE;    // 98

// ---------------------------------------------------------------------------
// CSR path kernels
// ---------------------------------------------------------------------------
__global__ __launch_bounds__(256) void k_zero_cnt(int* __restrict__ cnt) {
    int i = blockIdx.x * 256 + threadIdx.x;
    if (i < N_NODES) cnt[i] = 0;
}

__global__ __launch_bounds__(256) void k_hist(const int* __restrict__ dst,
                                              int* __restrict__ cnt) {
    int e = blockIdx.x * 256 + threadIdx.x;
    if (e < N_EDGES) atomicAdd(&cnt[dst[e]], 1);
}

// Block-level exclusive scan, tile = 1024 (256 thr x 4). Writes local-exclusive
// starts and per-block totals.
__global__ __launch_bounds__(256) void k_scan1(const int* __restrict__ cnt,
                                               int* __restrict__ starts,
                                               int* __restrict__ bsum) {
    __shared__ int s[256];
    const int tid  = threadIdx.x;
    const int base = blockIdx.x * SCAN_TILE + tid * 4;
    int c[4];
    int tsum = 0;
#pragma unroll
    for (int i = 0; i < 4; ++i) {
        c[i] = (base + i < N_NODES) ? cnt[base + i] : 0;
        tsum += c[i];
    }
    s[tid] = tsum;
    __syncthreads();
    for (int off = 1; off < 256; off <<= 1) {
        int u = (tid >= off) ? s[tid - off] : 0;
        __syncthreads();
        s[tid] += u;
        __syncthreads();
    }
    int run = s[tid] - tsum;   // exclusive prefix of this thread's chunk
#pragma unroll
    for (int i = 0; i < 4; ++i) {
        if (base + i < N_NODES) starts[base + i] = run;
        run += c[i];
    }
    if (tid == 255) bsum[blockIdx.x] = s[255];
}

// Scan the (<=128) block sums. One block of 128 threads.
__global__ __launch_bounds__(128) void k_scan2(const int* __restrict__ bsum,
                                               int* __restrict__ boff) {
    __shared__ int s[128];
    const int tid = threadIdx.x;
    int v = (tid < NB_SCAN) ? bsum[tid] : 0;
    s[tid] = v;
    __syncthreads();
    for (int off = 1; off < 128; off <<= 1) {
        int u = (tid >= off) ? s[tid - off] : 0;
        __syncthreads();
        s[tid] += u;
        __syncthreads();
    }
    boff[tid] = s[tid] - v;    // exclusive
}

// Add block offsets; produce final starts and a cursor copy for the fill.
__global__ __launch_bounds__(256) void k_scan3(int* __restrict__ starts,
                                               const int* __restrict__ boff,
                                               int* __restrict__ cursor) {
    const int base = blockIdx.x * SCAN_TILE + threadIdx.x * 4;
    const int off  = boff[blockIdx.x];
#pragma unroll
    for (int i = 0; i < 4; ++i) {
        int idx = base + i;
        if (idx < N_NODES) {
            int v = starts[idx] + off;
            starts[idx] = v;
            cursor[idx] = v;
        }
    }
    if (blockIdx.x == 0 && threadIdx.x == 0) starts[N_NODES] = N_EDGES;
}

// Scatter {src, weight} into CSR order.
__global__ __launch_bounds__(256) void k_fill(const int* __restrict__ src,
                                              const int* __restrict__ dst,
                                              const float* __restrict__ ew,
                                              int* __restrict__ cursor,
                                              uint2* __restrict__ entries) {
    int e = blockIdx.x * 256 + threadIdx.x;
    if (e >= N_EDGES) return;
    int d = dst[e];
    int pos = atomicAdd(&cursor[d], 1);
    entries[pos] = make_uint2((unsigned)src[e], __float_as_uint(ew[e]));
}

// Mean-aggregate incoming edges. One wave per node: 4 groups of 16 lanes,
// each group handles one edge per iteration; lane gl covers features 4gl..4gl+3.
__global__ __launch_bounds__(256) void k_agg(const float4* __restrict__ feat4,
                                             const int* __restrict__ starts,
                                             const uint2* __restrict__ entries,
                                             float4* __restrict__ agg4) {
    const int wave = threadIdx.x >> 6;
    const int lane = threadIdx.x & 63;
    const int n = blockIdx.x * 4 + wave;
    if (n >= N_NODES) return;
    const int group = lane >> 4;
    const int gl    = lane & 15;
    const int s0 = starts[n];
    const int s1 = starts[n + 1];

    float4 acc = make_float4(0.f, 0.f, 0.f, 0.f);
    for (int e = s0 + group; e < s1; e += 4) {
        uint2 en = entries[e];
        float w  = __uint_as_float(en.y);
        float4 v = feat4[(size_t)en.x * 16 + gl];
        acc.x = fmaf(v.x, w, acc.x);
        acc.y = fmaf(v.y, w, acc.y);
        acc.z = fmaf(v.z, w, acc.z);
        acc.w = fmaf(v.w, w, acc.w);
    }
    // reduce the 4 group partials (xor 16, 32)
#pragma unroll
    for (int m = 16; m <= 32; m <<= 1) {
        acc.x += __shfl_xor(acc.x, m);
        acc.y += __shfl_xor(acc.y, m);
        acc.z += __shfl_xor(acc.z, m);
        acc.w += __shfl_xor(acc.w, m);
    }
    if (group == 0) {
        const float inv = 1.0f / fmaxf((float)(s1 - s0), 1.0f);
        acc.x *= inv; acc.y *= inv; acc.z *= inv; acc.w *= inv;
        agg4[(size_t)n * 16 + gl] = acc;
    }
}

// Finalize: out[n,:] = [feat_n || agg_n] @ W2t + bias, W2t[j][k] combined.
// 64-node tile per block; X tile (32 KB) + W (32 KB) in LDS; wave w computes
// nodes 16w..16w+15, lane j = output column. X reads are wave-uniform
// (broadcast, conflict-free); W reads amortized over 16 nodes.
__global__ __launch_bounds__(256) void k_final(const float4* __restrict__ feat4,
                                               const float4* __restrict__ agg4,
                                               const float* __restrict__ Wn,
                                               const float* __restrict__ Ws,
                                               const float* __restrict__ bias,
                                               float* __restrict__ out) {
    __shared__ float xt[64 * 128];   // 32 KB
    __shared__ float wt[64 * 128];   // 32 KB
    const int tid   = threadIdx.x;
    const int node0 = blockIdx.x * 64;

    for (int idx = tid; idx < 64 * 128; idx += 256) {
        int j = idx >> 7, k = idx & 127;
        wt[idx] = (k < D) ? Ws[j * D + k] : Wn[j * D + (k - D)];
    }
    float4* xt4 = (float4*)xt;
    for (int idx = tid; idx < 64 * 32; idx += 256) {
        int m = idx >> 5, q = idx & 31;
        int n = node0 + m;
        float4 v = make_float4(0.f, 0.f, 0.f, 0.f);
        if (n < N_NODES)
            v = (q < 16) ? feat4[(size_t)n * 16 + q] : agg4[(size_t)n * 16 + (q - 16)];
        xt4[m * 32 + q] = v;
    }
    __syncthreads();

    const int j  = tid & 63;   // output column (lane)
    const int mg = tid >> 6;   // wave id -> node subgroup
    const float b = bias[j];
    float acc[16];
#pragma unroll
    for (int i = 0; i < 16; ++i) acc[i] = 0.f;

    for (int k = 0; k < 128; k += 4) {
        float4 wv = *(const float4*)&wt[j * 128 + k];
#pragma unroll
        for (int i = 0; i < 16; ++i) {
            float4 xv = *(const float4*)&xt[(mg * 16 + i) * 128 + k];
            acc[i] = fmaf(wv.x, xv.x, acc[i]);
            acc[i] = fmaf(wv.y, xv.y, acc[i]);
            acc[i] = fmaf(wv.z, xv.z, acc[i]);
            acc[i] = fmaf(wv.w, xv.w, acc[i]);
        }
    }
#pragma unroll
    for (int i = 0; i < 16; ++i) {
        int n = node0 + mg * 16 + i;
        if (n < N_NODES) out[(size_t)n * D + j] = acc[i] + b;
    }
}

// ---------------------------------------------------------------------------
// Fallback path (R1): atomic scatter + shuffle finalize. Used only if the
// provided workspace is too small for the CSR build.
// ---------------------------------------------------------------------------
__global__ __launch_bounds__(256) void fb_zero(float4* __restrict__ out4,
                                               float* __restrict__ deg) {
    const int stride = gridDim.x * blockDim.x;
    int i = blockIdx.x * blockDim.x + threadIdx.x;
    const int total4 = (N_NODES * D) / 4;
    for (int idx = i; idx < total4; idx += stride)
        out4[idx] = make_float4(0.f, 0.f, 0.f, 0.f);
    for (int idx = i; idx < N_NODES; idx += stride)
        deg[idx] = 0.f;
}

__global__ __launch_bounds__(256) void fb_scatter(
    const float* __restrict__ feat, const int* __restrict__ src,
    const int* __restrict__ dst, const float* __restrict__ ew,
    float* __restrict__ out, float* __restrict__ deg) {
    const int gid  = blockIdx.x * blockDim.x + threadIdx.x;
    const int e    = gid >> 6;
    const int lane = gid & 63;
    if (e >= N_EDGES) return;
    const int s = src[e];
    const int d = dst[e];
    const float w = ew[e];
    atomicAdd(&out[(size_t)d * D + lane], feat[(size_t)s * D + lane] * w);
    if (lane == 0) atomicAdd(&deg[d], 1.0f);
}

__global__ __launch_bounds__(256) void fb_finalize(
    const float* __restrict__ feat, const float* __restrict__ Wn,
    const float* __restrict__ Ws, const float* __restrict__ bias,
    const float* __restrict__ deg, float* __restrict__ out) {
    __shared__ float lWn[D * 65];
    __shared__ float lWs[D * 65];
    for (int idx = threadIdx.x; idx < D * D; idx += 256) {
        const int r = idx >> 6, c = idx & 63;
        lWn[r * 65 + c] = Wn[idx];
        lWs[r * 65 + c] = Ws[idx];
    }
    __syncthreads();
    const int wave = threadIdx.x >> 6;
    const int lane = threadIdx.x & 63;
    const int n = blockIdx.x * 4 + wave;
    if (n >= N_NODES) return;
    const float f  = feat[(size_t)n * D + lane];
    const float sv = out[(size_t)n * D + lane];
    const float inv = 1.0f / fmaxf(deg[n], 1.0f);
    float acc_s = 0.f, acc_n = 0.f;
#pragma unroll
    for (int k = 0; k < D; ++k) {
        acc_s += __shfl(f, k)  * lWs[lane * 65 + k];
        acc_n += __shfl(sv, k) * lWn[lane * 65 + k];
    }
    out[(size_t)n * D + lane] = acc_s + acc_n * inv + bias[lane];
}

// ---------------------------------------------------------------------------
extern "C" void kernel_launch(void* const* d_in, const int* in_sizes, int n_in,
                              void* d_out, int out_size, void* d_ws, size_t ws_size,
                              hipStream_t stream) {
    const float* feat = (const float*)d_in[0];
    const int*   src  = (const int*)  d_in[1];
    const int*   dst  = (const int*)  d_in[2];
    const float* ew   = (const float*)d_in[3];
    const float* Wn   = (const float*)d_in[4];
    const float* Ws   = (const float*)d_in[5];
    const float* bias = (const float*)d_in[6];
    float* out = (float*)d_out;
    char* ws = (char*)d_ws;

    if (ws_size >= WS_NEEDED) {
        int*   starts  = (int*)(ws + OFF_STARTS);
        int*   cursor  = (int*)(ws + OFF_CURSOR);   // also used as cnt
        int*   bsum    = (int*)(ws + OFF_BSUM);
        int*   boff    = (int*)(ws + OFF_BOFF);
        uint2* entries = (uint2*)(ws + OFF_ENTRIES);
        float* agg     = (float*)(ws + OFF_AGG);

        const int eb = (N_EDGES + 255) / 256;     // 6250
        const int nb = (N_NODES + 255) / 256;     // 391

        k_zero_cnt<<<nb, 256, 0, stream>>>(cursor);
        k_hist<<<eb, 256, 0, stream>>>(dst, cursor);
        k_scan1<<<NB_SCAN, 256, 0, stream>>>(cursor, starts, bsum);
        k_scan2<<<1, 128, 0, stream>>>(bsum, boff);
        k_scan3<<<NB_SCAN, 256, 0, stream>>>(starts, boff, cursor);
        k_fill<<<eb, 256, 0, stream>>>(src, dst, ew, cursor, entries);
        k_agg<<<(N_NODES + 3) / 4, 256, 0, stream>>>((const float4*)feat, starts,
                                                     entries, (float4*)agg);
        k_final<<<(N_NODES + 63) / 64, 256, 0, stream>>>((const float4*)feat,
                                                         (const float4*)agg,
                                                         Wn, Ws, bias, out);
    } else {
        float* deg = (float*)d_ws;
        fb_zero<<<2048, 256, 0, stream>>>((float4*)out, deg);
        fb_scatter<<<(N_EDGES * 64) / 256, 256, 0, stream>>>(feat, src, dst, ew, out, deg);
        fb_finalize<<<(N_NODES + 3) / 4, 256, 0, stream>>>(feat, Wn, Ws, bias, deg, out);
    }
}